// Round 1
// baseline (6288.299 us; speedup 1.0000x reference)
//
#include <hip/hip_runtime.h>
#include <math.h>

#define B_ 4
#define L_ 321
#define D_ 192
#define DI_ 384
#define E_ 768      // 2*DI
#define R_ 12
#define N_ 16
#define DEPTH_ 24
#define XD 44       // R + 2N

__device__ __forceinline__ float silu_f(float x) { return x / (1.f + __expf(-x)); }

// ---------------- patch embed + cls + pos ----------------
// grid: B_*L_ blocks, 192 threads (one per output channel d)
__global__ void patch_kernel(const float* __restrict__ xs, const float* __restrict__ xt,
                             const float* __restrict__ pw, const float* __restrict__ pb,
                             const float* __restrict__ cls, const float* __restrict__ pos,
                             float* __restrict__ hidden, float* __restrict__ residual) {
    int blk = blockIdx.x;
    int b = blk / L_, t = blk % L_;
    int d = threadIdx.x;
    residual[(size_t)(b*L_ + t)*D_ + d] = 0.f;   // zero-init residual
    if (t == 160) {
        hidden[(size_t)(b*L_ + t)*D_ + d] = cls[d] + pos[t*D_ + d];
        return;
    }
    int p_all = (t < 160) ? t : t - 1;
    __shared__ float patch[768];
    const float* src;
    int i, j, W;
    if (p_all < 64) { int p = p_all; i = p >> 3; j = p & 7; W = 128; src = xt + (size_t)b*3*128*128; }
    else            { int p = p_all - 64; i = p >> 4; j = p & 15; W = 256; src = xs + (size_t)b*3*256*256; }
    for (int m = d; m < 768; m += 192) {
        int c = m >> 8, rem = m & 255, pp = rem >> 4, qq = rem & 15;
        patch[m] = src[(size_t)(c*W + i*16 + pp)*W + j*16 + qq];
    }
    __syncthreads();
    float acc = 0.f;
    const float* wrow = pw + (size_t)d*768;
    for (int m = 0; m < 768; ++m) acc = fmaf(patch[m], wrow[m], acc);
    hidden[(size_t)(b*L_ + t)*D_ + d] = acc + pb[d] + pos[t*D_ + d];
}

// ---------------- residual += hidden; hn = rmsnorm(residual)*normw ----------------
// grid: B_*L_ blocks, 256 threads
__global__ void prenorm_kernel(float* __restrict__ residual, const float* __restrict__ hidden,
                               const float* __restrict__ normw, float* __restrict__ hn) {
    int row = blockIdx.x;
    int tid = threadIdx.x;
    __shared__ float red[256];
    float v = 0.f;
    if (tid < D_) {
        v = residual[(size_t)row*D_ + tid] + hidden[(size_t)row*D_ + tid];
        residual[(size_t)row*D_ + tid] = v;
    }
    red[tid] = v * v;
    __syncthreads();
    for (int s = 128; s > 0; s >>= 1) { if (tid < s) red[tid] += red[tid + s]; __syncthreads(); }
    float scale = rsqrtf(red[0] / (float)D_ + 1e-5f);
    if (tid < D_) hn[(size_t)row*D_ + tid] = v * scale * normw[tid];
}

// ---------------- final: out = rmsnorm(hidden+residual)*normw_f ----------------
__global__ void final_kernel(const float* __restrict__ residual, const float* __restrict__ hidden,
                             const float* __restrict__ normw_f, float* __restrict__ out) {
    int row = blockIdx.x;
    int tid = threadIdx.x;
    __shared__ float red[256];
    float v = 0.f;
    if (tid < D_) v = residual[(size_t)row*D_ + tid] + hidden[(size_t)row*D_ + tid];
    red[tid] = v * v;
    __syncthreads();
    for (int s = 128; s > 0; s >>= 1) { if (tid < s) red[tid] += red[tid + s]; __syncthreads(); }
    float scale = rsqrtf(red[0] / (float)D_ + 1e-5f);
    if (tid < D_) out[(size_t)row*D_ + tid] = v * scale * normw_f[tid];
}

// ---------------- generic C = A * B^T  (A: MxK, B: NxK, row-major) ----------------
__global__ void gemm_nt(const float* __restrict__ A, const float* __restrict__ B,
                        float* __restrict__ C, int M, int N, int K) {
    __shared__ float As[16][16];
    __shared__ float Bs[16][17];
    int tx = threadIdx.x, ty = threadIdx.y;
    int m = blockIdx.y * 16 + ty;
    int nb = blockIdx.x * 16;
    int n = nb + tx;
    float acc = 0.f;
    for (int k0 = 0; k0 < K; k0 += 16) {
        As[ty][tx] = (m < M) ? A[(size_t)m*K + k0 + tx] : 0.f;
        int brow = nb + ty;
        Bs[ty][tx] = (brow < N) ? B[(size_t)brow*K + k0 + tx] : 0.f;
        __syncthreads();
#pragma unroll
        for (int kk = 0; kk < 16; ++kk) acc = fmaf(As[ty][kk], Bs[tx][kk], acc);
        __syncthreads();
    }
    if (m < M && n < N) C[(size_t)m*N + n] = acc;
}

// C = (0.5*(A0+A1)) * B^T
__global__ void gemm_avg_nt(const float* __restrict__ A0, const float* __restrict__ A1,
                            const float* __restrict__ B, float* __restrict__ C,
                            int M, int N, int K) {
    __shared__ float As[16][16];
    __shared__ float Bs[16][17];
    int tx = threadIdx.x, ty = threadIdx.y;
    int m = blockIdx.y * 16 + ty;
    int nb = blockIdx.x * 16;
    int n = nb + tx;
    float acc = 0.f;
    for (int k0 = 0; k0 < K; k0 += 16) {
        As[ty][tx] = (m < M) ? 0.5f*(A0[(size_t)m*K + k0 + tx] + A1[(size_t)m*K + k0 + tx]) : 0.f;
        int brow = nb + ty;
        Bs[ty][tx] = (brow < N) ? B[(size_t)brow*K + k0 + tx] : 0.f;
        __syncthreads();
#pragma unroll
        for (int kk = 0; kk < 16; ++kk) acc = fmaf(As[ty][kk], Bs[tx][kk], acc);
        __syncthreads();
    }
    if (m < M && n < N) C[(size_t)m*N + n] = acc;
}

// ---------------- causal conv (k=4) + silu, both directions ----------------
// grid: B_*L_ blocks, 384 threads (d)
__global__ void conv_kernel(const float* __restrict__ xz,
                            const float* __restrict__ cw, const float* __restrict__ cb,
                            const float* __restrict__ cwb, const float* __restrict__ cbb,
                            float* __restrict__ xc_f, float* __restrict__ xc_b) {
    int blk = blockIdx.x;
    int b = blk / L_, l = blk % L_;
    int d = threadIdx.x;
    const float* xbase = xz + (size_t)b*L_*E_ + d;   // x part = first DI_ of E_
    float acc = cb[d];
#pragma unroll
    for (int k = 0; k < 4; ++k) {
        int t = l - 3 + k;
        if (t >= 0) acc = fmaf(cw[d*4 + k], xbase[(size_t)t*E_], acc);
    }
    xc_f[(size_t)(b*L_ + l)*DI_ + d] = silu_f(acc);
    float accb = cbb[d];
#pragma unroll
    for (int k = 0; k < 4; ++k) {
        int t = l - 3 + k;
        if (t >= 0) accb = fmaf(cwb[d*4 + k], xbase[(size_t)(L_ - 1 - t)*E_], accb);
    }
    xc_b[(size_t)(b*L_ + l)*DI_ + d] = silu_f(accb);
}

// ---------------- delta = softplus(dt @ Wdt^T + bdt) ----------------
// grid: (B_*L_, 2), 384 threads
__global__ void delta_kernel(const float* __restrict__ xdbl_f, const float* __restrict__ xdbl_b,
                             const float* __restrict__ Wdt, const float* __restrict__ bdt,
                             const float* __restrict__ Wdtb, const float* __restrict__ bdtb,
                             float* __restrict__ delta_f, float* __restrict__ delta_b) {
    int row = blockIdx.x;
    int br  = blockIdx.y;
    int d   = threadIdx.x;
    const float* xd = br ? xdbl_b : xdbl_f;
    const float* W  = br ? Wdtb : Wdt;
    const float* bb = br ? bdtb : bdt;
    float* outp     = br ? delta_b : delta_f;
    __shared__ float dt[R_];
    if (d < R_) dt[d] = xd[(size_t)row*XD + d];
    __syncthreads();
    float acc = bb[d];
#pragma unroll
    for (int r = 0; r < R_; ++r) acc = fmaf(dt[r], W[d*R_ + r], acc);
    float sp = fmaxf(acc, 0.f) + log1pf(__expf(-fabsf(acc)));
    outp[(size_t)row*DI_ + d] = sp;
}

// ---------------- selective scan (sequential over L), both dirs ----------------
// grid: (B_, 2), 384 threads (d). h[16] in registers.
__global__ void scan_kernel(const float* __restrict__ xc_f, const float* __restrict__ xc_b,
                            const float* __restrict__ xdbl_f, const float* __restrict__ xdbl_b,
                            const float* __restrict__ delta_f, const float* __restrict__ delta_b,
                            const float* __restrict__ xz,
                            const float* __restrict__ Alog, const float* __restrict__ Dpf,
                            const float* __restrict__ Alogb, const float* __restrict__ Dpb,
                            float* __restrict__ y_f, float* __restrict__ y_b) {
    int b = blockIdx.x, br = blockIdx.y;
    int d = threadIdx.x;
    const float* xc = br ? xc_b : xc_f;
    const float* xd = br ? xdbl_b : xdbl_f;
    const float* de = br ? delta_b : delta_f;
    const float* Al = br ? Alogb : Alog;
    const float* Dpp = br ? Dpb : Dpf;
    float* y = br ? y_b : y_f;

    float a[N_];
#pragma unroll
    for (int n = 0; n < N_; ++n) a[n] = -__expf(Al[d*N_ + n]);
    float h[N_];
#pragma unroll
    for (int n = 0; n < N_; ++n) h[n] = 0.f;
    float dpv = Dpp[d];

    for (int l = 0; l < L_; ++l) {
        size_t row = (size_t)b*L_ + l;
        float dv = de[row*DI_ + d];
        float u  = xc[row*DI_ + d];
        float du = dv * u;
        float yv = 0.f;
#pragma unroll
        for (int n = 0; n < N_; ++n) {
            float bm = xd[row*XD + R_ + n];
            float cm = xd[row*XD + R_ + N_ + n];
            h[n] = fmaf(__expf(dv * a[n]), h[n], du * bm);
            yv = fmaf(h[n], cm, yv);
        }
        yv = fmaf(dpv, u, yv);
        int lo = br ? (L_ - 1 - l) : l;
        float zv = xz[((size_t)b*L_ + lo)*E_ + DI_ + d];
        y[((size_t)b*L_ + lo)*DI_ + d] = yv * silu_f(zv);
    }
}

extern "C" void kernel_launch(void* const* d_in, const int* in_sizes, int n_in,
                              void* d_out, int out_size, void* d_ws, size_t ws_size,
                              hipStream_t stream) {
    const float* xs     = (const float*)d_in[0];
    const float* xt     = (const float*)d_in[1];
    const float* pw     = (const float*)d_in[2];
    const float* pb     = (const float*)d_in[3];
    const float* cls    = (const float*)d_in[4];
    const float* pos    = (const float*)d_in[5];
    const float* Win    = (const float*)d_in[6];
    const float* convw  = (const float*)d_in[7];
    const float* convb  = (const float*)d_in[8];
    const float* Wx     = (const float*)d_in[9];
    const float* Wdt    = (const float*)d_in[10];
    const float* bdt    = (const float*)d_in[11];
    const float* Alog   = (const float*)d_in[12];
    const float* Dp     = (const float*)d_in[13];
    const float* convwb = (const float*)d_in[14];
    const float* convbb = (const float*)d_in[15];
    const float* Wxb    = (const float*)d_in[16];
    const float* Wdtb   = (const float*)d_in[17];
    const float* bdtb   = (const float*)d_in[18];
    const float* Alogb  = (const float*)d_in[19];
    const float* Dpb    = (const float*)d_in[20];
    const float* Wout   = (const float*)d_in[21];
    const float* normw  = (const float*)d_in[22];
    const float* normwf = (const float*)d_in[23];
    float* out = (float*)d_out;

    float* ws = (float*)d_ws;
    size_t off = 0;
    auto alloc = [&](size_t n) { float* p = ws + off; off += n; return p; };
    const size_t BL = (size_t)B_ * L_;
    float* residual = alloc(BL * D_);
    float* hidden   = alloc(BL * D_);
    float* hn       = alloc(BL * D_);
    float* xzb      = alloc(BL * E_);
    float* xc_f     = alloc(BL * DI_);
    float* xc_b     = alloc(BL * DI_);
    float* xdbl_f   = alloc(BL * XD);
    float* xdbl_b   = alloc(BL * XD);
    float* delta_f  = alloc(BL * DI_);
    float* delta_b  = alloc(BL * DI_);
    float* y_f      = alloc(BL * DI_);
    float* y_b      = alloc(BL * DI_);
    (void)ws_size; (void)in_sizes; (void)n_in; (void)out_size;

    patch_kernel<<<dim3(B_ * L_), dim3(192), 0, stream>>>(xs, xt, pw, pb, cls, pos, hidden, residual);

    for (int layer = 0; layer < DEPTH_; ++layer) {
        const float* Win_l   = Win   + (size_t)layer * E_ * D_;
        const float* cw_l    = convw + (size_t)layer * DI_ * 4;
        const float* cb_l    = convb + (size_t)layer * DI_;
        const float* cwb_l   = convwb + (size_t)layer * DI_ * 4;
        const float* cbb_l   = convbb + (size_t)layer * DI_;
        const float* Wx_l    = Wx    + (size_t)layer * XD * DI_;
        const float* Wxb_l   = Wxb   + (size_t)layer * XD * DI_;
        const float* Wdt_l   = Wdt   + (size_t)layer * DI_ * R_;
        const float* Wdtb_l  = Wdtb  + (size_t)layer * DI_ * R_;
        const float* bdt_l   = bdt   + (size_t)layer * DI_;
        const float* bdtb_l  = bdtb  + (size_t)layer * DI_;
        const float* Alog_l  = Alog  + (size_t)layer * DI_ * N_;
        const float* Alogb_l = Alogb + (size_t)layer * DI_ * N_;
        const float* Dp_l    = Dp    + (size_t)layer * DI_;
        const float* Dpb_l   = Dpb   + (size_t)layer * DI_;
        const float* Wout_l  = Wout  + (size_t)layer * D_ * DI_;
        const float* normw_l = normw + (size_t)layer * D_;

        prenorm_kernel<<<dim3((int)BL), dim3(256), 0, stream>>>(residual, hidden, normw_l, hn);
        gemm_nt<<<dim3(E_ / 16, (int)((BL + 15) / 16)), dim3(16, 16), 0, stream>>>(hn, Win_l, xzb, (int)BL, E_, D_);
        conv_kernel<<<dim3((int)BL), dim3(DI_), 0, stream>>>(xzb, cw_l, cb_l, cwb_l, cbb_l, xc_f, xc_b);
        gemm_nt<<<dim3((XD + 15) / 16, (int)((BL + 15) / 16)), dim3(16, 16), 0, stream>>>(xc_f, Wx_l, xdbl_f, (int)BL, XD, DI_);
        gemm_nt<<<dim3((XD + 15) / 16, (int)((BL + 15) / 16)), dim3(16, 16), 0, stream>>>(xc_b, Wxb_l, xdbl_b, (int)BL, XD, DI_);
        delta_kernel<<<dim3((int)BL, 2), dim3(DI_), 0, stream>>>(xdbl_f, xdbl_b, Wdt_l, bdt_l, Wdtb_l, bdtb_l, delta_f, delta_b);
        scan_kernel<<<dim3(B_, 2), dim3(DI_), 0, stream>>>(xc_f, xc_b, xdbl_f, xdbl_b, delta_f, delta_b, xzb,
                                                           Alog_l, Dp_l, Alogb_l, Dpb_l, y_f, y_b);
        gemm_avg_nt<<<dim3(D_ / 16, (int)((BL + 15) / 16)), dim3(16, 16), 0, stream>>>(y_f, y_b, Wout_l, hidden, (int)BL, D_, DI_);
    }

    final_kernel<<<dim3((int)BL), dim3(256), 0, stream>>>(residual, hidden, normwf, out);
}

// Round 2
// 2914.577 us; speedup vs baseline: 2.1575x; 2.1575x over previous
//
#include <hip/hip_runtime.h>
#include <math.h>

#define B_ 4
#define L_ 321
#define D_ 192
#define DI_ 384
#define E_ 768      // 2*DI
#define R_ 12
#define N_ 16
#define DEPTH_ 24
#define XD 44       // R + 2N

#define NC_ 21      // number of scan chunks
#define LC_ 16      // chunk length (NC_*LC_ >= L_)

__device__ __forceinline__ float silu_f(float x) { return x / (1.f + __expf(-x)); }

// ---------------- patch embed + cls + pos ----------------
__global__ void patch_kernel(const float* __restrict__ xs, const float* __restrict__ xt,
                             const float* __restrict__ pw, const float* __restrict__ pb,
                             const float* __restrict__ cls, const float* __restrict__ pos,
                             float* __restrict__ hidden, float* __restrict__ residual) {
    int blk = blockIdx.x;
    int b = blk / L_, t = blk % L_;
    int d = threadIdx.x;
    residual[(size_t)(b*L_ + t)*D_ + d] = 0.f;   // zero-init residual
    if (t == 160) {
        hidden[(size_t)(b*L_ + t)*D_ + d] = cls[d] + pos[t*D_ + d];
        return;
    }
    int p_all = (t < 160) ? t : t - 1;
    __shared__ float patch[768];
    const float* src;
    int i, j, W;
    if (p_all < 64) { int p = p_all; i = p >> 3; j = p & 7; W = 128; src = xt + (size_t)b*3*128*128; }
    else            { int p = p_all - 64; i = p >> 4; j = p & 15; W = 256; src = xs + (size_t)b*3*256*256; }
    for (int m = d; m < 768; m += 192) {
        int c = m >> 8, rem = m & 255, pp = rem >> 4, qq = rem & 15;
        patch[m] = src[(size_t)(c*W + i*16 + pp)*W + j*16 + qq];
    }
    __syncthreads();
    float acc = 0.f;
    const float* wrow = pw + (size_t)d*768;
    for (int m = 0; m < 768; ++m) acc = fmaf(patch[m], wrow[m], acc);
    hidden[(size_t)(b*L_ + t)*D_ + d] = acc + pb[d] + pos[t*D_ + d];
}

// ---------------- residual += hidden; hn = rmsnorm(residual)*normw ----------------
__global__ void prenorm_kernel(float* __restrict__ residual, const float* __restrict__ hidden,
                               const float* __restrict__ normw, float* __restrict__ hn) {
    int row = blockIdx.x;
    int tid = threadIdx.x;
    __shared__ float red[256];
    float v = 0.f;
    if (tid < D_) {
        v = residual[(size_t)row*D_ + tid] + hidden[(size_t)row*D_ + tid];
        residual[(size_t)row*D_ + tid] = v;
    }
    red[tid] = v * v;
    __syncthreads();
    for (int s = 128; s > 0; s >>= 1) { if (tid < s) red[tid] += red[tid + s]; __syncthreads(); }
    float scale = rsqrtf(red[0] / (float)D_ + 1e-5f);
    if (tid < D_) hn[(size_t)row*D_ + tid] = v * scale * normw[tid];
}

// ---------------- final: out = rmsnorm(hidden+residual)*normw_f ----------------
__global__ void final_kernel(const float* __restrict__ residual, const float* __restrict__ hidden,
                             const float* __restrict__ normw_f, float* __restrict__ out) {
    int row = blockIdx.x;
    int tid = threadIdx.x;
    __shared__ float red[256];
    float v = 0.f;
    if (tid < D_) v = residual[(size_t)row*D_ + tid] + hidden[(size_t)row*D_ + tid];
    red[tid] = v * v;
    __syncthreads();
    for (int s = 128; s > 0; s >>= 1) { if (tid < s) red[tid] += red[tid + s]; __syncthreads(); }
    float scale = rsqrtf(red[0] / (float)D_ + 1e-5f);
    if (tid < D_) out[(size_t)row*D_ + tid] = v * scale * normw_f[tid];
}

// ---------------- generic C = A * B^T  (A: MxK, B: NxK, row-major) ----------------
__global__ void gemm_nt(const float* __restrict__ A, const float* __restrict__ B,
                        float* __restrict__ C, int M, int N, int K) {
    __shared__ float As[16][16];
    __shared__ float Bs[16][17];
    int tx = threadIdx.x, ty = threadIdx.y;
    int m = blockIdx.y * 16 + ty;
    int nb = blockIdx.x * 16;
    int n = nb + tx;
    float acc = 0.f;
    for (int k0 = 0; k0 < K; k0 += 16) {
        As[ty][tx] = (m < M) ? A[(size_t)m*K + k0 + tx] : 0.f;
        int brow = nb + ty;
        Bs[ty][tx] = (brow < N) ? B[(size_t)brow*K + k0 + tx] : 0.f;
        __syncthreads();
#pragma unroll
        for (int kk = 0; kk < 16; ++kk) acc = fmaf(As[ty][kk], Bs[tx][kk], acc);
        __syncthreads();
    }
    if (m < M && n < N) C[(size_t)m*N + n] = acc;
}

// C = (0.5*(A0+A1)) * B^T
__global__ void gemm_avg_nt(const float* __restrict__ A0, const float* __restrict__ A1,
                            const float* __restrict__ B, float* __restrict__ C,
                            int M, int N, int K) {
    __shared__ float As[16][16];
    __shared__ float Bs[16][17];
    int tx = threadIdx.x, ty = threadIdx.y;
    int m = blockIdx.y * 16 + ty;
    int nb = blockIdx.x * 16;
    int n = nb + tx;
    float acc = 0.f;
    for (int k0 = 0; k0 < K; k0 += 16) {
        As[ty][tx] = (m < M) ? 0.5f*(A0[(size_t)m*K + k0 + tx] + A1[(size_t)m*K + k0 + tx]) : 0.f;
        int brow = nb + ty;
        Bs[ty][tx] = (brow < N) ? B[(size_t)brow*K + k0 + tx] : 0.f;
        __syncthreads();
#pragma unroll
        for (int kk = 0; kk < 16; ++kk) acc = fmaf(As[ty][kk], Bs[tx][kk], acc);
        __syncthreads();
    }
    if (m < M && n < N) C[(size_t)m*N + n] = acc;
}

// ---------------- causal conv (k=4) + silu, both directions ----------------
__global__ void conv_kernel(const float* __restrict__ xz,
                            const float* __restrict__ cw, const float* __restrict__ cb,
                            const float* __restrict__ cwb, const float* __restrict__ cbb,
                            float* __restrict__ xc_f, float* __restrict__ xc_b) {
    int blk = blockIdx.x;
    int b = blk / L_, l = blk % L_;
    int d = threadIdx.x;
    const float* xbase = xz + (size_t)b*L_*E_ + d;   // x part = first DI_ of E_
    float acc = cb[d];
#pragma unroll
    for (int k = 0; k < 4; ++k) {
        int t = l - 3 + k;
        if (t >= 0) acc = fmaf(cw[d*4 + k], xbase[(size_t)t*E_], acc);
    }
    xc_f[(size_t)(b*L_ + l)*DI_ + d] = silu_f(acc);
    float accb = cbb[d];
#pragma unroll
    for (int k = 0; k < 4; ++k) {
        int t = l - 3 + k;
        if (t >= 0) accb = fmaf(cwb[d*4 + k], xbase[(size_t)(L_ - 1 - t)*E_], accb);
    }
    xc_b[(size_t)(b*L_ + l)*DI_ + d] = silu_f(accb);
}

// ---------------- delta = softplus(dt @ Wdt^T + bdt) ----------------
__global__ void delta_kernel(const float* __restrict__ xdbl_f, const float* __restrict__ xdbl_b,
                             const float* __restrict__ Wdt, const float* __restrict__ bdt,
                             const float* __restrict__ Wdtb, const float* __restrict__ bdtb,
                             float* __restrict__ delta_f, float* __restrict__ delta_b) {
    int row = blockIdx.x;
    int br  = blockIdx.y;
    int d   = threadIdx.x;
    const float* xd = br ? xdbl_b : xdbl_f;
    const float* W  = br ? Wdtb : Wdt;
    const float* bb = br ? bdtb : bdt;
    float* outp     = br ? delta_b : delta_f;
    __shared__ float dt[R_];
    if (d < R_) dt[d] = xd[(size_t)row*XD + d];
    __syncthreads();
    float acc = bb[d];
#pragma unroll
    for (int r = 0; r < R_; ++r) acc = fmaf(dt[r], W[d*R_ + r], acc);
    float sp = fmaxf(acc, 0.f) + log1pf(__expf(-fabsf(acc)));
    outp[(size_t)row*DI_ + d] = sp;
}

// ---------------- chunked parallel scan ----------------
// Phase 1: per-chunk local scan -> hloc (h with h_in=0) and aprod (prod of dA)
// grid: (NC_, B_, 2), block DI_ threads
__global__ void scan_part1(const float* __restrict__ xc_f, const float* __restrict__ xc_b,
                           const float* __restrict__ xdbl_f, const float* __restrict__ xdbl_b,
                           const float* __restrict__ delta_f, const float* __restrict__ delta_b,
                           const float* __restrict__ Alog, const float* __restrict__ Alogb,
                           float* __restrict__ hloc, float* __restrict__ aprod) {
    int c = blockIdx.x, b = blockIdx.y, br = blockIdx.z;
    int d = threadIdx.x;
    const float* xc = br ? xc_b : xc_f;
    const float* xd = br ? xdbl_b : xdbl_f;
    const float* de = br ? delta_b : delta_f;
    const float* Al = br ? Alogb : Alog;
    __shared__ float sdv[LC_][DI_];
    __shared__ float su[LC_][DI_];
    __shared__ float sB[LC_][N_];
    int lbeg = c * LC_;
    int lend = min(lbeg + LC_, L_);
    int len = lend - lbeg;
    for (int l2 = 0; l2 < len; ++l2) {
        size_t row = (size_t)b*L_ + lbeg + l2;
        sdv[l2][d] = de[row*DI_ + d];
        su[l2][d]  = xc[row*DI_ + d];
    }
    for (int idx = d; idx < len*N_; idx += DI_) {
        int l2 = idx >> 4, n = idx & 15;
        sB[l2][n] = xd[((size_t)b*L_ + lbeg + l2)*XD + R_ + n];
    }
    __syncthreads();
    float a[N_];
#pragma unroll
    for (int n = 0; n < N_; ++n) a[n] = -__expf(Al[d*N_ + n]);
    float h[N_], ap[N_];
#pragma unroll
    for (int n = 0; n < N_; ++n) { h[n] = 0.f; ap[n] = 1.f; }
    for (int l2 = 0; l2 < len; ++l2) {
        float dv = sdv[l2][d], u = su[l2][d], du = dv * u;
#pragma unroll
        for (int n = 0; n < N_; ++n) {
            float e = __expf(dv * a[n]);
            h[n] = fmaf(e, h[n], du * sB[l2][n]);
            ap[n] *= e;
        }
    }
    size_t base = (((size_t)(b*2 + br)*NC_ + c)*N_)*DI_ + d;
#pragma unroll
    for (int n = 0; n < N_; ++n) {
        hloc[base + (size_t)n*DI_]  = h[n];
        aprod[base + (size_t)n*DI_] = ap[n];
    }
}

// Phase 2: serial combine over chunks -> hin (state entering each chunk)
// grid: B_*2*N_*DI_ / 256 blocks, 256 threads
__global__ void scan_combine(const float* __restrict__ hloc, const float* __restrict__ aprod,
                             float* __restrict__ hin) {
    int g = blockIdx.x * blockDim.x + threadIdx.x;   // over B_*2*N_*DI_
    int bb = g / (N_ * DI_);
    int rem = g % (N_ * DI_);
    float hrun = 0.f;
    for (int c = 0; c < NC_; ++c) {
        size_t idx = ((size_t)bb*NC_ + c)*N_*DI_ + rem;
        hin[idx] = hrun;
        hrun = fmaf(aprod[idx], hrun, hloc[idx]);
    }
}

// Phase 3: re-scan each chunk from hin, emit y = (h.C + Dp*u) * silu(z)
// grid: (NC_, B_, 2), block DI_ threads
__global__ void scan_part3(const float* __restrict__ xc_f, const float* __restrict__ xc_b,
                           const float* __restrict__ xdbl_f, const float* __restrict__ xdbl_b,
                           const float* __restrict__ delta_f, const float* __restrict__ delta_b,
                           const float* __restrict__ xz,
                           const float* __restrict__ Alog, const float* __restrict__ Alogb,
                           const float* __restrict__ Dpf, const float* __restrict__ Dpb,
                           const float* __restrict__ hin,
                           float* __restrict__ y_f, float* __restrict__ y_b) {
    int c = blockIdx.x, b = blockIdx.y, br = blockIdx.z;
    int d = threadIdx.x;
    const float* xc = br ? xc_b : xc_f;
    const float* xd = br ? xdbl_b : xdbl_f;
    const float* de = br ? delta_b : delta_f;
    const float* Al = br ? Alogb : Alog;
    const float* Dpp = br ? Dpb : Dpf;
    float* y = br ? y_b : y_f;
    __shared__ float sdv[LC_][DI_];
    __shared__ float su[LC_][DI_];
    __shared__ float sB[LC_][N_];
    __shared__ float sC[LC_][N_];
    int lbeg = c * LC_;
    int lend = min(lbeg + LC_, L_);
    int len = lend - lbeg;
    for (int l2 = 0; l2 < len; ++l2) {
        size_t row = (size_t)b*L_ + lbeg + l2;
        sdv[l2][d] = de[row*DI_ + d];
        su[l2][d]  = xc[row*DI_ + d];
    }
    for (int idx = d; idx < len*N_; idx += DI_) {
        int l2 = idx >> 4, n = idx & 15;
        size_t row = (size_t)b*L_ + lbeg + l2;
        sB[l2][n] = xd[row*XD + R_ + n];
        sC[l2][n] = xd[row*XD + R_ + N_ + n];
    }
    __syncthreads();
    float a[N_];
#pragma unroll
    for (int n = 0; n < N_; ++n) a[n] = -__expf(Al[d*N_ + n]);
    float h[N_];
    size_t hbase = (((size_t)(b*2 + br)*NC_ + c)*N_)*DI_ + d;
#pragma unroll
    for (int n = 0; n < N_; ++n) h[n] = hin[hbase + (size_t)n*DI_];
    float dpv = Dpp[d];
    for (int l2 = 0; l2 < len; ++l2) {
        float dv = sdv[l2][d], u = su[l2][d], du = dv * u;
        float yv = 0.f;
#pragma unroll
        for (int n = 0; n < N_; ++n) {
            float e = __expf(dv * a[n]);
            h[n] = fmaf(e, h[n], du * sB[l2][n]);
            yv = fmaf(h[n], sC[l2][n], yv);
        }
        yv = fmaf(dpv, u, yv);
        int lo = br ? (L_ - 1 - (lbeg + l2)) : (lbeg + l2);
        float zv = xz[((size_t)b*L_ + lo)*E_ + DI_ + d];
        y[((size_t)b*L_ + lo)*DI_ + d] = yv * silu_f(zv);
    }
}

extern "C" void kernel_launch(void* const* d_in, const int* in_sizes, int n_in,
                              void* d_out, int out_size, void* d_ws, size_t ws_size,
                              hipStream_t stream) {
    const float* xs     = (const float*)d_in[0];
    const float* xt     = (const float*)d_in[1];
    const float* pw     = (const float*)d_in[2];
    const float* pb     = (const float*)d_in[3];
    const float* cls    = (const float*)d_in[4];
    const float* pos    = (const float*)d_in[5];
    const float* Win    = (const float*)d_in[6];
    const float* convw  = (const float*)d_in[7];
    const float* convb  = (const float*)d_in[8];
    const float* Wx     = (const float*)d_in[9];
    const float* Wdt    = (const float*)d_in[10];
    const float* bdt    = (const float*)d_in[11];
    const float* Alog   = (const float*)d_in[12];
    const float* Dp     = (const float*)d_in[13];
    const float* convwb = (const float*)d_in[14];
    const float* convbb = (const float*)d_in[15];
    const float* Wxb    = (const float*)d_in[16];
    const float* Wdtb   = (const float*)d_in[17];
    const float* bdtb   = (const float*)d_in[18];
    const float* Alogb  = (const float*)d_in[19];
    const float* Dpb    = (const float*)d_in[20];
    const float* Wout   = (const float*)d_in[21];
    const float* normw  = (const float*)d_in[22];
    const float* normwf = (const float*)d_in[23];
    float* out = (float*)d_out;

    float* ws = (float*)d_ws;
    size_t off = 0;
    auto alloc = [&](size_t n) { float* p = ws + off; off += n; return p; };
    const size_t BL = (size_t)B_ * L_;
    const size_t CHNK = (size_t)B_ * 2 * NC_ * N_ * DI_;
    float* residual = alloc(BL * D_);
    float* hidden   = alloc(BL * D_);
    float* hn       = alloc(BL * D_);
    float* xzb      = alloc(BL * E_);
    float* xc_f     = alloc(BL * DI_);
    float* xc_b     = alloc(BL * DI_);
    float* xdbl_f   = alloc(BL * XD);
    float* xdbl_b   = alloc(BL * XD);
    float* delta_f  = alloc(BL * DI_);
    float* delta_b  = alloc(BL * DI_);
    float* y_f      = alloc(BL * DI_);
    float* y_b      = alloc(BL * DI_);
    float* hloc     = alloc(CHNK);
    float* aprod    = alloc(CHNK);
    float* hin      = alloc(CHNK);
    (void)ws_size; (void)in_sizes; (void)n_in; (void)out_size;

    patch_kernel<<<dim3(B_ * L_), dim3(192), 0, stream>>>(xs, xt, pw, pb, cls, pos, hidden, residual);

    for (int layer = 0; layer < DEPTH_; ++layer) {
        const float* Win_l   = Win   + (size_t)layer * E_ * D_;
        const float* cw_l    = convw + (size_t)layer * DI_ * 4;
        const float* cb_l    = convb + (size_t)layer * DI_;
        const float* cwb_l   = convwb + (size_t)layer * DI_ * 4;
        const float* cbb_l   = convbb + (size_t)layer * DI_;
        const float* Wx_l    = Wx    + (size_t)layer * XD * DI_;
        const float* Wxb_l   = Wxb   + (size_t)layer * XD * DI_;
        const float* Wdt_l   = Wdt   + (size_t)layer * DI_ * R_;
        const float* Wdtb_l  = Wdtb  + (size_t)layer * DI_ * R_;
        const float* bdt_l   = bdt   + (size_t)layer * DI_;
        const float* bdtb_l  = bdtb  + (size_t)layer * DI_;
        const float* Alog_l  = Alog  + (size_t)layer * DI_ * N_;
        const float* Alogb_l = Alogb + (size_t)layer * DI_ * N_;
        const float* Dp_l    = Dp    + (size_t)layer * DI_;
        const float* Dpb_l   = Dpb   + (size_t)layer * DI_;
        const float* Wout_l  = Wout  + (size_t)layer * D_ * DI_;
        const float* normw_l = normw + (size_t)layer * D_;

        prenorm_kernel<<<dim3((int)BL), dim3(256), 0, stream>>>(residual, hidden, normw_l, hn);
        gemm_nt<<<dim3(E_ / 16, (int)((BL + 15) / 16)), dim3(16, 16), 0, stream>>>(hn, Win_l, xzb, (int)BL, E_, D_);
        conv_kernel<<<dim3((int)BL), dim3(DI_), 0, stream>>>(xzb, cw_l, cb_l, cwb_l, cbb_l, xc_f, xc_b);
        gemm_nt<<<dim3((XD + 15) / 16, (int)((BL + 15) / 16)), dim3(16, 16), 0, stream>>>(xc_f, Wx_l, xdbl_f, (int)BL, XD, DI_);
        gemm_nt<<<dim3((XD + 15) / 16, (int)((BL + 15) / 16)), dim3(16, 16), 0, stream>>>(xc_b, Wxb_l, xdbl_b, (int)BL, XD, DI_);
        delta_kernel<<<dim3((int)BL, 2), dim3(DI_), 0, stream>>>(xdbl_f, xdbl_b, Wdt_l, bdt_l, Wdtb_l, bdtb_l, delta_f, delta_b);
        scan_part1<<<dim3(NC_, B_, 2), dim3(DI_), 0, stream>>>(xc_f, xc_b, xdbl_f, xdbl_b, delta_f, delta_b,
                                                               Alog_l, Alogb_l, hloc, aprod);
        scan_combine<<<dim3((B_*2*N_*DI_)/256), dim3(256), 0, stream>>>(hloc, aprod, hin);
        scan_part3<<<dim3(NC_, B_, 2), dim3(DI_), 0, stream>>>(xc_f, xc_b, xdbl_f, xdbl_b, delta_f, delta_b, xzb,
                                                               Alog_l, Alogb_l, Dp_l, Dpb_l, hin, y_f, y_b);
        gemm_avg_nt<<<dim3(D_ / 16, (int)((BL + 15) / 16)), dim3(16, 16), 0, stream>>>(y_f, y_b, Wout_l, hidden, (int)BL, D_, DI_);
    }

    final_kernel<<<dim3((int)BL), dim3(256), 0, stream>>>(residual, hidden, normwf, out);
}